// Round 1
// baseline (937.089 us; speedup 1.0000x reference)
//
#include <hip/hip_runtime.h>

#define N_NODES 100000
#define N_EDGES 800000

// ---------------------------------------------------------------------------
// GEMM: C[n][j] = sum_d A[n][d] * B[j][d] + bias[j]
// A: M x 128 row-major; B: Ncols x 128 row-major (both K-contiguous).
// BM=64, BN=64, BK=64; 256 threads; 4x4 register micro-tile.
// LDS pad 65: compute reads land 2-way bank aliased (free on CDNA4).
// ---------------------------------------------------------------------------
__global__ __launch_bounds__(256) void gemm_abt(
    const float* __restrict__ A, const float* __restrict__ B,
    const float* __restrict__ bias, float* __restrict__ C,
    int M, int ldc)
{
    __shared__ float As[64][65];
    __shared__ float Bs[64][65];
    const int t = threadIdx.x;
    const int tn = t & 15;          // node group (16 groups x 4 rows)
    const int tj = t >> 4;          // col group  (16 groups x 4 cols)
    const int n0 = blockIdx.x * 64;
    const int j0 = blockIdx.y * 64;

    float acc[4][4] = {};

    for (int kb = 0; kb < 128; kb += 64) {
        // stage 64x64 of A and B: 1024 float4 each, 4 per thread
        #pragma unroll
        for (int it = 0; it < 4; ++it) {
            int f4  = t + it * 256;
            int row = f4 >> 4;
            int c4  = (f4 & 15) << 2;
            int gr  = n0 + row;
            if (gr >= M) gr = M - 1;   // clamp tail (stores are guarded)
            float4 va = *reinterpret_cast<const float4*>(
                A + (size_t)gr * 128 + kb + c4);
            As[row][c4 + 0] = va.x; As[row][c4 + 1] = va.y;
            As[row][c4 + 2] = va.z; As[row][c4 + 3] = va.w;
            float4 vb = *reinterpret_cast<const float4*>(
                B + (size_t)(j0 + row) * 128 + kb + c4);
            Bs[row][c4 + 0] = vb.x; Bs[row][c4 + 1] = vb.y;
            Bs[row][c4 + 2] = vb.z; Bs[row][c4 + 3] = vb.w;
        }
        __syncthreads();

        #pragma unroll 4
        for (int d = 0; d < 64; ++d) {
            float a[4], b[4];
            #pragma unroll
            for (int i = 0; i < 4; ++i) a[i] = As[tn * 4 + i][d];
            #pragma unroll
            for (int j = 0; j < 4; ++j) b[j] = Bs[tj * 4 + j][d];
            #pragma unroll
            for (int i = 0; i < 4; ++i)
                #pragma unroll
                for (int j = 0; j < 4; ++j)
                    acc[i][j] += a[i] * b[j];
        }
        __syncthreads();
    }

    #pragma unroll
    for (int i = 0; i < 4; ++i) {
        int n = n0 + tn * 4 + i;
        if (n >= M) continue;
        #pragma unroll
        for (int j = 0; j < 4; ++j) {
            int jj = j0 + tj * 4 + j;
            C[(size_t)n * ldc + jj] = acc[i][j] + bias[jj];
        }
    }
}

// ---------------------------------------------------------------------------
// Edge scores: one thread per (edge, head).
// qkv row layout: per head h (48 floats): q [h*48, +16), k [h*48+16, +16),
// v [h*48+32, +16).  scores bounded (|s| < ~3) => skip segment_max:
// probs = exp(s)/sum(exp(s)) is max-shift invariant, no overflow possible.
// ---------------------------------------------------------------------------
__global__ __launch_bounds__(256) void edge_scores(
    const float* __restrict__ qkv, const int* __restrict__ src,
    const int* __restrict__ dst, float* __restrict__ P,
    float* __restrict__ denom)
{
    int g = blockIdx.x * 256 + threadIdx.x;
    if (g >= N_EDGES * 8) return;
    int e = g >> 3, h = g & 7;
    int se = src[e], de = dst[e];
    const float4* kp = reinterpret_cast<const float4*>(
        qkv + (size_t)se * 384 + h * 48 + 16);
    const float4* qp = reinterpret_cast<const float4*>(
        qkv + (size_t)de * 384 + h * 48);
    float s = 0.f;
    #pragma unroll
    for (int i = 0; i < 4; ++i) {
        float4 kv = kp[i], qv = qp[i];
        s += kv.x * qv.x + kv.y * qv.y + kv.z * qv.z + kv.w * qv.w;
    }
    float p = __expf(s * 0.25f);   // coef = 1/sqrt(16)
    P[g] = p;
    atomicAdd(denom + (size_t)de * 8 + h, p);
}

// ---------------------------------------------------------------------------
// Aggregate: one thread per (edge, channel c in [0,128)).
// Wave lanes cover 64 consecutive channels of one edge -> the 64 atomicAdds
// target 256 contiguous bytes of attn[dst] (coalesced at L2).
// ---------------------------------------------------------------------------
__global__ __launch_bounds__(256) void edge_aggregate(
    const float* __restrict__ qkv, const int* __restrict__ src,
    const int* __restrict__ dst, const float* __restrict__ P,
    const float* __restrict__ denom, float* __restrict__ attn)
{
    int g = blockIdx.x * 256 + threadIdx.x;
    if (g >= N_EDGES * 128) return;
    int e = g >> 7, c = g & 127;
    int h = c >> 4, d = c & 15;
    int se = src[e], de = dst[e];
    float w = P[e * 8 + h] / denom[(size_t)de * 8 + h];
    float v = qkv[(size_t)se * 384 + h * 48 + 32 + d];
    atomicAdd(attn + (size_t)de * 128 + c, v * w);
}

// ---------------------------------------------------------------------------
// Workspace layout (floats):
//   qkv   [0,            38,400,000)   100000*384
//   P     [38,400,000,   44,800,000)   800000*8
//   denom [44,800,000,   45,600,000)   100000*8
//   attn  [45,600,000,   58,400,000)   100000*128
// total 233.6 MB
// ---------------------------------------------------------------------------
extern "C" void kernel_launch(void* const* d_in, const int* in_sizes, int n_in,
                              void* d_out, int out_size, void* d_ws, size_t ws_size,
                              hipStream_t stream) {
    const float* x     = (const float*)d_in[0];
    const float* W_qkv = (const float*)d_in[1];
    const float* b_qkv = (const float*)d_in[2];
    const float* W_out = (const float*)d_in[3];
    const float* b_out = (const float*)d_in[4];
    const int*   src   = (const int*)d_in[5];
    const int*   dst   = (const int*)d_in[6];
    float* out  = (float*)d_out;

    float* ws    = (float*)d_ws;
    float* qkv   = ws;
    float* P     = ws + 38400000;
    float* denom = ws + 44800000;
    float* attn  = ws + 45600000;

    // denom + attn are adjacent: zero both with one memset (ws is poisoned
    // 0xAA before every timed launch).
    hipMemsetAsync(denom, 0, (size_t)(800000 + 12800000) * sizeof(float), stream);

    dim3 g1((N_NODES + 63) / 64, 384 / 64);
    gemm_abt<<<g1, 256, 0, stream>>>(x, W_qkv, b_qkv, qkv, N_NODES, 384);

    edge_scores<<<(N_EDGES * 8) / 256, 256, 0, stream>>>(qkv, src, dst, P, denom);

    edge_aggregate<<<(N_EDGES * 128) / 256, 256, 0, stream>>>(
        qkv, src, dst, P, denom, attn);

    dim3 g4((N_NODES + 63) / 64, 128 / 64);
    gemm_abt<<<g4, 256, 0, stream>>>(attn, W_out, b_out, out, N_NODES, 128);
}

// Round 2
// 366.967 us; speedup vs baseline: 2.5536x; 2.5536x over previous
//
#include <hip/hip_runtime.h>
#include <hip/hip_bf16.h>

#define N_NODES 100000
#define N_EDGES 800000
#define NB1 98   // ceil(100000/1024)

typedef __attribute__((ext_vector_type(8))) short short8;
typedef __attribute__((ext_vector_type(4))) float f32x4;

__device__ __forceinline__ float bf2f(ushort u) {
    union { unsigned i; float f; } x; x.i = ((unsigned)u) << 16; return x.f;
}
__device__ __forceinline__ ushort f2bf(float f) {
    union { float f; unsigned u; } x { f };
    unsigned r = x.u + 0x7FFF + ((x.u >> 16) & 1);   // RNE
    return (ushort)(r >> 16);
}

// ---------------------------------------------------------------------------
// fp32 -> bf16 convert, 4 elems/thread
// ---------------------------------------------------------------------------
__global__ __launch_bounds__(256) void cvt_bf16(
    const float* __restrict__ in, ushort* __restrict__ out, int n4)
{
    int i = blockIdx.x * 256 + threadIdx.x;
    if (i >= n4) return;
    float4 v = reinterpret_cast<const float4*>(in)[i];
    ushort4 o;
    o.x = f2bf(v.x); o.y = f2bf(v.y); o.z = f2bf(v.z); o.w = f2bf(v.w);
    reinterpret_cast<ushort4*>(out)[i] = o;
}

// ---------------------------------------------------------------------------
// MFMA GEMM: C[M x Ncols] = A(bf16 M x 128) @ B(bf16 Ncols x 128)^T + bias.
// Block tile 128x128, 4 waves (2x2), each wave 64x64 via 4x4 frags of
// mfma_f32_16x16x32_bf16. BK=64, 2 k-iters. LDS rows padded to 72 bf16.
// C/D layout (m89-verified): col = lane&15, row = (lane>>4)*4 + reg.
// A/B frag: m/n = lane&15, k = (lane>>4)*8 + j (A,B symmetric => any
// consistent k-bijection is correct).
// ---------------------------------------------------------------------------
template<int OUT_BF16>
__global__ __launch_bounds__(256) void gemm_mfma(
    const ushort* __restrict__ A, const ushort* __restrict__ B,
    const float* __restrict__ bias, void* __restrict__ Cv,
    int M, int ldc)
{
    __shared__ ushort As[128][72];
    __shared__ ushort Bs[128][72];
    const int t = threadIdx.x;
    const int lane = t & 63;
    const int w = t >> 6;
    const int wm = w >> 1, wn = w & 1;
    const int n0 = blockIdx.x * 128;
    const int j0 = blockIdx.y * 128;

    f32x4 acc[4][4];
    #pragma unroll
    for (int i = 0; i < 4; ++i)
        #pragma unroll
        for (int j = 0; j < 4; ++j) acc[i][j] = (f32x4){0.f, 0.f, 0.f, 0.f};

    for (int kb = 0; kb < 128; kb += 64) {
        #pragma unroll
        for (int it = 0; it < 4; ++it) {
            int c = it * 256 + t;
            int row = c >> 3, g = c & 7;
            int ar = n0 + row; if (ar >= M) ar = M - 1;  // stores guarded
            *reinterpret_cast<short8*>(&As[row][g * 8]) =
                *reinterpret_cast<const short8*>(A + (size_t)ar * 128 + kb + g * 8);
            *reinterpret_cast<short8*>(&Bs[row][g * 8]) =
                *reinterpret_cast<const short8*>(B + (size_t)(j0 + row) * 128 + kb + g * 8);
        }
        __syncthreads();
        #pragma unroll
        for (int kf = 0; kf < 2; ++kf) {
            short8 af[4], bfr[4];
            #pragma unroll
            for (int mf = 0; mf < 4; ++mf)
                af[mf] = *reinterpret_cast<const short8*>(
                    &As[wm * 64 + mf * 16 + (lane & 15)][kf * 32 + (lane >> 4) * 8]);
            #pragma unroll
            for (int nf = 0; nf < 4; ++nf)
                bfr[nf] = *reinterpret_cast<const short8*>(
                    &Bs[wn * 64 + nf * 16 + (lane & 15)][kf * 32 + (lane >> 4) * 8]);
            #pragma unroll
            for (int mf = 0; mf < 4; ++mf)
                #pragma unroll
                for (int nf = 0; nf < 4; ++nf)
                    acc[mf][nf] = __builtin_amdgcn_mfma_f32_16x16x32_bf16(
                        af[mf], bfr[nf], acc[mf][nf], 0, 0, 0);
        }
        __syncthreads();
    }

    const int r0 = (lane >> 4) * 4, cc = lane & 15;
    #pragma unroll
    for (int mf = 0; mf < 4; ++mf) {
        #pragma unroll
        for (int j = 0; j < 4; ++j) {
            int row = n0 + wm * 64 + mf * 16 + r0 + j;
            if (row >= M) continue;
            #pragma unroll
            for (int nf = 0; nf < 4; ++nf) {
                int col = j0 + wn * 64 + nf * 16 + cc;
                float v = acc[mf][nf][j] + bias[col];
                if (OUT_BF16)
                    ((ushort*)Cv)[(size_t)row * ldc + col] = f2bf(v);
                else
                    ((float*)Cv)[(size_t)row * ldc + col] = v;
            }
        }
    }
}

// ---------------------------------------------------------------------------
// CSR build: histogram -> block scan -> global scan -> add -> fill
// ---------------------------------------------------------------------------
__global__ __launch_bounds__(256) void count_dst(
    const int* __restrict__ dst, int* __restrict__ counts)
{
    int e = blockIdx.x * 256 + threadIdx.x;
    if (e < N_EDGES) atomicAdd(&counts[dst[e]], 1);
}

__global__ __launch_bounds__(1024) void scan1(
    const int* __restrict__ counts, int* __restrict__ row_start,
    int* __restrict__ bsums)
{
    __shared__ int sd[1024];
    int t = threadIdx.x, i = blockIdx.x * 1024 + t;
    int v = (i < N_NODES) ? counts[i] : 0;
    sd[t] = v; __syncthreads();
    for (int off = 1; off < 1024; off <<= 1) {
        int x = (t >= off) ? sd[t - off] : 0;
        __syncthreads();
        sd[t] += x;
        __syncthreads();
    }
    if (i < N_NODES) row_start[i] = sd[t] - v;   // exclusive within block
    if (t == 1023) bsums[blockIdx.x] = sd[1023];
}

__global__ __launch_bounds__(128) void scan2(
    const int* __restrict__ bsums, int* __restrict__ boffs)
{
    __shared__ int sd[128];
    int t = threadIdx.x;
    int v = (t < NB1) ? bsums[t] : 0;
    sd[t] = v; __syncthreads();
    for (int off = 1; off < 128; off <<= 1) {
        int x = (t >= off) ? sd[t - off] : 0;
        __syncthreads();
        sd[t] += x;
        __syncthreads();
    }
    if (t < NB1) boffs[t] = sd[t] - v;
}

__global__ __launch_bounds__(256) void scan3(
    int* __restrict__ row_start, const int* __restrict__ boffs)
{
    int i = blockIdx.x * 256 + threadIdx.x;
    if (i < N_NODES) row_start[i] += boffs[i >> 10];
    if (i == 0) row_start[N_NODES] = N_EDGES;
}

__global__ __launch_bounds__(256) void fill_csr(
    const int* __restrict__ src, const int* __restrict__ dst,
    const int* __restrict__ row_start, int* __restrict__ fillc,
    int* __restrict__ csr_src)
{
    int e = blockIdx.x * 256 + threadIdx.x;
    if (e >= N_EDGES) return;
    int d = dst[e];
    int pos = row_start[d] + atomicAdd(&fillc[d], 1);
    csr_src[pos] = src[e];
}

// ---------------------------------------------------------------------------
// Fused attention: one wave per dst node. lane = h*8 + d2 owns channels
// (h, 2*d2, 2*d2+1). q in regs; per edge gather k||v (adjacent 32B+32B),
// 3x shfl_xor score-reduce within 8-lane head group, online p-weighted
// accumulate. Softmax max-shift skipped: |s| <~ 4 so exp can't overflow,
// probs are shift-invariant. Single coalesced bf16 write; no atomics.
// qkv row layout per head h: q [h*48,+16) k [+16) v [+16).
// ---------------------------------------------------------------------------
__global__ __launch_bounds__(256) void fused_attn(
    const ushort* __restrict__ qkvb, const int* __restrict__ row_start,
    const int* __restrict__ csr_src, ushort* __restrict__ attnb)
{
    int node = (blockIdx.x * 256 + threadIdx.x) >> 6;
    if (node >= N_NODES) return;
    int lane = threadIdx.x & 63;
    int h = lane >> 3, d2 = lane & 7;
    const int qoff = h * 48 + 2 * d2;

    unsigned qb = *reinterpret_cast<const unsigned*>(qkvb + (size_t)node * 384 + qoff);
    float q0 = bf2f((ushort)qb), q1 = bf2f((ushort)(qb >> 16));

    int beg = row_start[node], end = row_start[node + 1];
    float denom = 0.f, a0 = 0.f, a1 = 0.f;
    for (int i = beg; i < end; ++i) {
        int s = csr_src[i];
        const ushort* rp = qkvb + (size_t)s * 384 + qoff + 16;
        unsigned kb = *reinterpret_cast<const unsigned*>(rp);
        unsigned vb = *reinterpret_cast<const unsigned*>(rp + 16);
        float ps = bf2f((ushort)kb) * q0 + bf2f((ushort)(kb >> 16)) * q1;
        ps += __shfl_xor(ps, 1);
        ps += __shfl_xor(ps, 2);
        ps += __shfl_xor(ps, 4);
        float p = __expf(ps * 0.25f);   // coef = 1/sqrt(16)
        denom += p;
        a0 += p * bf2f((ushort)vb);
        a1 += p * bf2f((ushort)(vb >> 16));
    }
    float inv = (end > beg) ? 1.f / denom : 0.f;   // deg-0 node -> zeros
    unsigned o = ((unsigned)f2bf(a1 * inv) << 16) | (unsigned)f2bf(a0 * inv);
    *reinterpret_cast<unsigned*>(attnb + (size_t)node * 128 + h * 16 + 2 * d2) = o;
}

// ---------------------------------------------------------------------------
// Workspace layout (bytes, all 16B-aligned), total ~132.5 MB:
//   xb      [0,           25,600,000)
//   qkvb    [25,600,000, 102,400,000)
//   attnb   [102,400,000,128,000,000)
//   Wqb     [128,000,000,128,098,304)
//   Wob     [128,098,304,128,131,072)
//   counts  [128,131,072,128,531,072)   \ zeroed by one memset
//   fill    [128,531,072,128,931,072)   /
//   rows    [128,931,072,129,331,088)   (N+1 ints, padded)
//   bsums   [129,331,088,129,331,600)
//   boffs   [129,331,600,129,332,112)
//   csr_src [129,332,112,132,532,112)
// ---------------------------------------------------------------------------
extern "C" void kernel_launch(void* const* d_in, const int* in_sizes, int n_in,
                              void* d_out, int out_size, void* d_ws, size_t ws_size,
                              hipStream_t stream) {
    const float* x     = (const float*)d_in[0];
    const float* W_qkv = (const float*)d_in[1];
    const float* b_qkv = (const float*)d_in[2];
    const float* W_out = (const float*)d_in[3];
    const float* b_out = (const float*)d_in[4];
    const int*   src   = (const int*)d_in[5];
    const int*   dst   = (const int*)d_in[6];
    float* out = (float*)d_out;

    char* w = (char*)d_ws;
    ushort* xb       = (ushort*)(w);
    ushort* qkvb     = (ushort*)(w + 25600000);
    ushort* attnb    = (ushort*)(w + 102400000);
    ushort* Wqb      = (ushort*)(w + 128000000);
    ushort* Wob      = (ushort*)(w + 128098304);
    int*    counts   = (int*)(w + 128131072);
    int*    fillc    = (int*)(w + 128531072);
    int*    row_start= (int*)(w + 128931072);
    int*    bsums    = (int*)(w + 129331088);
    int*    boffs    = (int*)(w + 129331600);
    int*    csr_src  = (int*)(w + 129332112);

    hipMemsetAsync(counts, 0, 800000, stream);  // counts + fill together

    cvt_bf16<<<12500, 256, 0, stream>>>(x, xb, 3200000);
    cvt_bf16<<<48, 256, 0, stream>>>(W_qkv, Wqb, 12288);
    cvt_bf16<<<16, 256, 0, stream>>>(W_out, Wob, 4096);

    gemm_mfma<1><<<dim3(782, 3), 256, 0, stream>>>(xb, Wqb, b_qkv, (void*)qkvb,
                                                   N_NODES, 384);

    count_dst<<<3125, 256, 0, stream>>>(dst, counts);
    scan1<<<NB1, 1024, 0, stream>>>(counts, row_start, bsums);
    scan2<<<1, 128, 0, stream>>>(bsums, boffs);
    scan3<<<391, 256, 0, stream>>>(row_start, boffs);
    fill_csr<<<3125, 256, 0, stream>>>(src, dst, row_start, fillc, csr_src);

    fused_attn<<<25000, 256, 0, stream>>>(qkvb, row_start, csr_src, attnb);

    gemm_mfma<0><<<dim3(782, 1), 256, 0, stream>>>(attnb, Wob, b_out, (void*)out,
                                                   N_NODES, 128);
}

// Round 4
// 312.687 us; speedup vs baseline: 2.9969x; 1.1736x over previous
//
#include <hip/hip_runtime.h>
#include <hip/hip_bf16.h>

#define N_NODES 100000
#define N_EDGES 800000
#define NB1 98   // ceil(100000/1024)

typedef __attribute__((ext_vector_type(8))) short short8;
typedef __attribute__((ext_vector_type(4))) float f32x4;

__device__ __forceinline__ float bf2f(ushort u) {
    union { unsigned i; float f; } x; x.i = ((unsigned)u) << 16; return x.f;
}
__device__ __forceinline__ ushort f2bf(float f) {
    union { float f; unsigned u; } x { f };
    unsigned r = x.u + 0x7FFF + ((x.u >> 16) & 1);   // RNE
    return (ushort)(r >> 16);
}

// ---------------------------------------------------------------------------
// fp32 -> bf16 convert, 4 elems/thread (weights only now)
// ---------------------------------------------------------------------------
__global__ __launch_bounds__(256) void cvt_bf16(
    const float* __restrict__ in, ushort* __restrict__ out, int n4)
{
    int i = blockIdx.x * 256 + threadIdx.x;
    if (i >= n4) return;
    float4 v = reinterpret_cast<const float4*>(in)[i];
    ushort4 o;
    o.x = f2bf(v.x); o.y = f2bf(v.y); o.z = f2bf(v.z); o.w = f2bf(v.w);
    reinterpret_cast<ushort4*>(out)[i] = o;
}

// ---------------------------------------------------------------------------
// Permute W_qkv rows (output channels) so the GEMM directly produces
// rows laid out [q(128) | k(128) | v(128)] with per-head channel d at
// h*16+d in each block. Also permutes the bias.
// Ref layout: out col j = h*48 + r, r<16: q_d=r, r<32: k_d=r-16, else v_d=r-32.
// ---------------------------------------------------------------------------
__global__ __launch_bounds__(128) void permute_w(
    const float* __restrict__ Wq, const float* __restrict__ bq,
    ushort* __restrict__ Wqb, float* __restrict__ bqp)
{
    int j = blockIdx.x;                   // 0..383
    int h = j / 48, r = j % 48;
    int p = (r < 16) ? h * 16 + r
          : (r < 32) ? 128 + h * 16 + (r - 16)
                     : 256 + h * 16 + (r - 32);
    const float* row = Wq + (size_t)j * 128;
    ushort* orow = Wqb + (size_t)p * 128;
    orow[threadIdx.x] = f2bf(row[threadIdx.x]);
    if (threadIdx.x == 0) bqp[p] = bq[j];
}

// ---------------------------------------------------------------------------
// MFMA GEMM: C[M x Ncols] = A(M x 128) @ B(bf16 Ncols x 128)^T + bias.
// A is fp32 (A_F32=1, converted during LDS staging) or bf16.
// Block tile 128x128, 4 waves (2x2), each wave 64x64 via 4x4 frags of
// mfma_f32_16x16x32_bf16. BK=64. LDS rows padded to 72 bf16.
// C/D layout (m89-verified): col = lane&15, row = (lane>>4)*4 + reg.
// ---------------------------------------------------------------------------
template<int A_F32, int OUT_BF16>
__global__ __launch_bounds__(256) void gemm_mfma(
    const void* __restrict__ Av, const ushort* __restrict__ B,
    const float* __restrict__ bias, void* __restrict__ Cv,
    int M, int ldc)
{
    __shared__ ushort As[128][72];
    __shared__ ushort Bs[128][72];
    const int t = threadIdx.x;
    const int lane = t & 63;
    const int w = t >> 6;
    const int wm = w >> 1, wn = w & 1;
    const int n0 = blockIdx.x * 128;
    const int j0 = blockIdx.y * 128;

    f32x4 acc[4][4];
    #pragma unroll
    for (int i = 0; i < 4; ++i)
        #pragma unroll
        for (int j = 0; j < 4; ++j) acc[i][j] = (f32x4){0.f, 0.f, 0.f, 0.f};

    for (int kb = 0; kb < 128; kb += 64) {
        #pragma unroll
        for (int it = 0; it < 4; ++it) {
            int c = it * 256 + t;
            int row = c >> 3, g = c & 7;           // 8 elems per chunk
            int ar = n0 + row; if (ar >= M) ar = M - 1;  // stores guarded
            if (A_F32) {
                const float* ap = (const float*)Av + (size_t)ar * 128 + kb + g * 8;
                float4 a0 = *reinterpret_cast<const float4*>(ap);
                float4 a1 = *reinterpret_cast<const float4*>(ap + 4);
                short8 o;
                o[0] = (short)f2bf(a0.x); o[1] = (short)f2bf(a0.y);
                o[2] = (short)f2bf(a0.z); o[3] = (short)f2bf(a0.w);
                o[4] = (short)f2bf(a1.x); o[5] = (short)f2bf(a1.y);
                o[6] = (short)f2bf(a1.z); o[7] = (short)f2bf(a1.w);
                *reinterpret_cast<short8*>(&As[row][g * 8]) = o;
            } else {
                *reinterpret_cast<short8*>(&As[row][g * 8]) =
                    *reinterpret_cast<const short8*>(
                        (const ushort*)Av + (size_t)ar * 128 + kb + g * 8);
            }
            *reinterpret_cast<short8*>(&Bs[row][g * 8]) =
                *reinterpret_cast<const short8*>(B + (size_t)(j0 + row) * 128 + kb + g * 8);
        }
        __syncthreads();
        #pragma unroll
        for (int kf = 0; kf < 2; ++kf) {
            short8 af[4], bfr[4];
            #pragma unroll
            for (int mf = 0; mf < 4; ++mf)
                af[mf] = *reinterpret_cast<const short8*>(
                    &As[wm * 64 + mf * 16 + (lane & 15)][kf * 32 + (lane >> 4) * 8]);
            #pragma unroll
            for (int nf = 0; nf < 4; ++nf)
                bfr[nf] = *reinterpret_cast<const short8*>(
                    &Bs[wn * 64 + nf * 16 + (lane & 15)][kf * 32 + (lane >> 4) * 8]);
            #pragma unroll
            for (int mf = 0; mf < 4; ++mf)
                #pragma unroll
                for (int nf = 0; nf < 4; ++nf)
                    acc[mf][nf] = __builtin_amdgcn_mfma_f32_16x16x32_bf16(
                        af[mf], bfr[nf], acc[mf][nf], 0, 0, 0);
        }
        __syncthreads();
    }

    const int r0 = (lane >> 4) * 4, cc = lane & 15;
    #pragma unroll
    for (int mf = 0; mf < 4; ++mf) {
        #pragma unroll
        for (int j = 0; j < 4; ++j) {
            int row = n0 + wm * 64 + mf * 16 + r0 + j;
            if (row >= M) continue;
            #pragma unroll
            for (int nf = 0; nf < 4; ++nf) {
                int col = j0 + wn * 64 + nf * 16 + cc;
                float v = acc[mf][nf][j] + bias[col];
                if (OUT_BF16)
                    ((ushort*)Cv)[(size_t)row * ldc + col] = f2bf(v);
                else
                    ((float*)Cv)[(size_t)row * ldc + col] = v;
            }
        }
    }
}

// ---------------------------------------------------------------------------
// CSR build: histogram -> block scan -> global scan -> add -> fill
// ---------------------------------------------------------------------------
__global__ __launch_bounds__(256) void count_dst(
    const int* __restrict__ dst, int* __restrict__ counts)
{
    int e = blockIdx.x * 256 + threadIdx.x;
    if (e < N_EDGES) atomicAdd(&counts[dst[e]], 1);
}

__global__ __launch_bounds__(1024) void scan1(
    const int* __restrict__ counts, int* __restrict__ row_start,
    int* __restrict__ bsums)
{
    __shared__ int sd[1024];
    int t = threadIdx.x, i = blockIdx.x * 1024 + t;
    int v = (i < N_NODES) ? counts[i] : 0;
    sd[t] = v; __syncthreads();
    for (int off = 1; off < 1024; off <<= 1) {
        int x = (t >= off) ? sd[t - off] : 0;
        __syncthreads();
        sd[t] += x;
        __syncthreads();
    }
    if (i < N_NODES) row_start[i] = sd[t] - v;   // exclusive within block
    if (t == 1023) bsums[blockIdx.x] = sd[1023];
}

__global__ __launch_bounds__(128) void scan2(
    const int* __restrict__ bsums, int* __restrict__ boffs)
{
    __shared__ int sd[128];
    int t = threadIdx.x;
    int v = (t < NB1) ? bsums[t] : 0;
    sd[t] = v; __syncthreads();
    for (int off = 1; off < 128; off <<= 1) {
        int x = (t >= off) ? sd[t - off] : 0;
        __syncthreads();
        sd[t] += x;
        __syncthreads();
    }
    if (t < NB1) boffs[t] = sd[t] - v;
}

__global__ __launch_bounds__(256) void scan3(
    int* __restrict__ row_start, const int* __restrict__ boffs)
{
    int i = blockIdx.x * 256 + threadIdx.x;
    if (i < N_NODES) row_start[i] += boffs[i >> 10];
    if (i == 0) row_start[N_NODES] = N_EDGES;
}

__global__ __launch_bounds__(256) void fill_csr(
    const int* __restrict__ src, const int* __restrict__ dst,
    const int* __restrict__ row_start, int* __restrict__ fillc,
    int* __restrict__ csr_src)
{
    int e = blockIdx.x * 256 + threadIdx.x;
    if (e >= N_EDGES) return;
    int d = dst[e];
    int pos = row_start[d] + atomicAdd(&fillc[d], 1);
    csr_src[pos] = src[e];
}

// ---------------------------------------------------------------------------
// Fused attention: one wave per dst node. Row layout [q|k|v], each 128ch
// with channel h*16+d. lane = h*8+d2 owns channels (h, 2d2, 2d2+1), i.e.
// byte offset lane*4 in each 256B block. Per edge: k||v is one contiguous
// 512B aligned block. Edge loop unrolled x4: 4 csr loads -> 8 independent
// gathers -> 4 interleaved score chains (MLP on the dependent-load chain).
// Softmax max-shift skipped (|s| < ~3, shift-invariant). No atomics.
// ---------------------------------------------------------------------------
__global__ __launch_bounds__(256) void fused_attn(
    const ushort* __restrict__ qkvp, const int* __restrict__ row_start,
    const int* __restrict__ csr_src, ushort* __restrict__ attnb)
{
    int node = (blockIdx.x * 256 + threadIdx.x) >> 6;
    if (node >= N_NODES) return;
    int lane = threadIdx.x & 63;

    unsigned qb = *reinterpret_cast<const unsigned*>(
        qkvp + (size_t)node * 384 + lane * 2);
    float q0 = bf2f((ushort)qb), q1 = bf2f((ushort)(qb >> 16));

    int beg = row_start[node], end = row_start[node + 1];
    float denom = 0.f, a0 = 0.f, a1 = 0.f;

#define GATHER(s, kk, vv) { \
        const ushort* rp = qkvp + (size_t)(s) * 384 + 128 + lane * 2; \
        kk = *reinterpret_cast<const unsigned*>(rp); \
        vv = *reinterpret_cast<const unsigned*>(rp + 128); }
#define EDGE(kk, vv) { \
        float ps = bf2f((ushort)(kk)) * q0 + bf2f((ushort)((kk) >> 16)) * q1; \
        ps += __shfl_xor(ps, 1); \
        ps += __shfl_xor(ps, 2); \
        ps += __shfl_xor(ps, 4); \
        float p = __expf(ps * 0.25f); \
        denom += p; \
        a0 += p * bf2f((ushort)(vv)); \
        a1 += p * bf2f((ushort)((vv) >> 16)); }

    int i = beg;
    for (; i + 4 <= end; i += 4) {
        int s0 = csr_src[i], s1 = csr_src[i + 1];
        int s2 = csr_src[i + 2], s3 = csr_src[i + 3];
        unsigned k0, v0, k1, v1, k2, v2, k3, v3;
        GATHER(s0, k0, v0); GATHER(s1, k1, v1);
        GATHER(s2, k2, v2); GATHER(s3, k3, v3);
        EDGE(k0, v0); EDGE(k1, v1); EDGE(k2, v2); EDGE(k3, v3);
    }
    for (; i < end; ++i) {
        int s = csr_src[i];
        unsigned kk, vv;
        GATHER(s, kk, vv);
        EDGE(kk, vv);
    }
#undef GATHER
#undef EDGE

    float inv = (end > beg) ? 1.f / denom : 0.f;   // deg-0 node -> zeros
    unsigned o = ((unsigned)f2bf(a1 * inv) << 16) | (unsigned)f2bf(a0 * inv);
    *reinterpret_cast<unsigned*>(attnb + (size_t)node * 128 + lane * 2) = o;
}

// ---------------------------------------------------------------------------
// Workspace layout (bytes, 16B-aligned), total ~107 MB:
//   qkvp     [0,           76,800,000)   100000*384 bf16  [q|k|v]
//   attnb    [76,800,000, 102,400,000)   100000*128 bf16
//   Wqb      [102,400,000,102,498,304)   384*128 bf16 (permuted)
//   Wob      [102,498,304,102,531,072)   128*128 bf16
//   bqp      [102,531,072,102,532,608)   384 f32 (permuted bias)
//   counts   [102,532,608,102,932,608)   \ zeroed by one memset
//   fillc    [102,932,608,103,332,608)   /
//   rows     [103,332,608,103,732,736)   N+1 ints (padded)
//   bsums    [103,732,736,103,733,248)
//   boffs    [103,733,248,103,733,760)
//   csr_src  [103,733,760,106,933,760)
// ---------------------------------------------------------------------------
extern "C" void kernel_launch(void* const* d_in, const int* in_sizes, int n_in,
                              void* d_out, int out_size, void* d_ws, size_t ws_size,
                              hipStream_t stream) {
    const float* x     = (const float*)d_in[0];
    const float* W_qkv = (const float*)d_in[1];
    const float* b_qkv = (const float*)d_in[2];
    const float* W_out = (const float*)d_in[3];
    const float* b_out = (const float*)d_in[4];
    const int*   src   = (const int*)d_in[5];
    const int*   dst   = (const int*)d_in[6];
    float* out = (float*)d_out;

    char* w = (char*)d_ws;
    ushort* qkvp     = (ushort*)(w);
    ushort* attnb    = (ushort*)(w + 76800000);
    ushort* Wqb      = (ushort*)(w + 102400000);
    ushort* Wob      = (ushort*)(w + 102498304);
    float*  bqp      = (float*)(w + 102531072);
    int*    counts   = (int*)(w + 102532608);
    int*    fillc    = (int*)(w + 102932608);
    int*    row_start= (int*)(w + 103332608);
    int*    bsums    = (int*)(w + 103732736);
    int*    boffs    = (int*)(w + 103733248);
    int*    csr_src  = (int*)(w + 103733760);

    hipMemsetAsync(counts, 0, 800000, stream);  // counts + fillc together

    permute_w<<<384, 128, 0, stream>>>(W_qkv, b_qkv, Wqb, bqp);
    cvt_bf16<<<16, 256, 0, stream>>>(W_out, Wob, 4096);

    // QKV projection: A = x (fp32, converted in staging), out bf16 [q|k|v]
    gemm_mfma<1, 1><<<dim3(782, 3), 256, 0, stream>>>(
        (const void*)x, Wqb, bqp, (void*)qkvp, N_NODES, 384);

    count_dst<<<3125, 256, 0, stream>>>(dst, counts);
    scan1<<<NB1, 1024, 0, stream>>>(counts, row_start, bsums);
    scan2<<<1, 128, 0, stream>>>(bsums, boffs);
    scan3<<<391, 256, 0, stream>>>(row_start, boffs);
    fill_csr<<<3125, 256, 0, stream>>>(src, dst, row_start, fillc, csr_src);

    fused_attn<<<25000, 256, 0, stream>>>(qkvp, row_start, csr_src, attnb);

    // Output projection: A = attnb (bf16), out fp32
    gemm_mfma<0, 0><<<dim3(782, 1), 256, 0, stream>>>(
        (const void*)attnb, Wob, b_out, (void*)out, N_NODES, 128);
}